// Round 4
// baseline (327.917 us; speedup 1.0000x reference)
//
#include <hip/hip_runtime.h>
#include <stdint.h>

typedef __attribute__((ext_vector_type(8))) short short8;
typedef __attribute__((ext_vector_type(8))) unsigned short ushort8;
typedef __attribute__((ext_vector_type(4))) float f32x4;
typedef __attribute__((ext_vector_type(16))) float f32x16;
typedef __attribute__((ext_vector_type(2))) unsigned int uint2v;

#define NNODES 4096
#define NEDGES 262144
#define DIM 128
#define NENT 50000
#define NENTP 50048  // padded to 782*64
#define NTILES 782   // ceil(50000/64)
#define NSPLIT 16    // y-splits; 16 x-blocks * 16 = 256 blocks = 1/CU (8 waves/CU)

__device__ __forceinline__ unsigned short f2bf(float f) {
  union { __bf16 b; unsigned short u; } c;
  c.b = (__bf16)f;   // RNE; gfx950 has HW bf16 cvt
  return c.u;
}

// ---------------- scatter pipeline: hist -> scan -> place -> aggregate ----------------
__global__ __launch_bounds__(256) void k_hist(
    const int* __restrict__ ei, int* __restrict__ cnt)
{
  int e = blockIdx.x * 256 + threadIdx.x;
  atomicAdd(&cnt[ei[NEDGES + e]], 1);
}

__global__ __launch_bounds__(1024) void k_scan(
    const int* __restrict__ cnt, int* __restrict__ off, int* __restrict__ cur)
{
  __shared__ int s[1024];
  int t = threadIdx.x;
  int4 v = reinterpret_cast<const int4*>(cnt)[t];
  int lsum = v.x + v.y + v.z + v.w;
  s[t] = lsum; __syncthreads();
  for (int d = 1; d < 1024; d <<= 1) {
    int a = (t >= d) ? s[t - d] : 0;
    __syncthreads();
    s[t] += a;
    __syncthreads();
  }
  int base = s[t] - lsum;  // exclusive prefix
  int4 o; o.x = base; o.y = base + v.x; o.z = o.y + v.y; o.w = o.z + v.z;
  reinterpret_cast<int4*>(off)[t] = o;
  reinterpret_cast<int4*>(cur)[t] = o;
  if (t == 1023) off[4096] = base + lsum;
}

__global__ __launch_bounds__(256) void k_place(
    const int* __restrict__ ei, const int* __restrict__ rid,
    const int* __restrict__ nf, int* __restrict__ cur, int* __restrict__ sorted)
{
  int e = blockIdx.x * 256 + threadIdx.x;
  int dst = ei[NEDGES + e];
  int pos = atomicAdd(&cur[dst], 1);
  sorted[pos] = ei[e] | (rid[e] << 12) | (nf[e] << 22);
}

// one node per block; 8 edge-slots x 32 float4-lanes (8 edges in flight, 16B gathers)
// fuses buildq: q = bf16(0.1*x + aggr)
__global__ __launch_bounds__(256) void k_aggr(
    const int* __restrict__ off, const int* __restrict__ sorted,
    const float* __restrict__ x, const float* __restrict__ rel,
    unsigned short* __restrict__ q)
{
  __shared__ float sAcc[8 * 132];   // slot-major, pad 132 -> conflict-free
  const int n = blockIdx.x;
  const int t = threadIdx.x;
  const int slot = t >> 5;          // 0..7
  const int c = t & 31;             // float4 chunk (dims 4c..4c+3)
  const int b = off[n], eN = off[n + 1];
  float4 acc = make_float4(0.f, 0.f, 0.f, 0.f);
  for (int i = b + slot; i < eN; i += 8) {
    int p = sorted[i];
    float4 xv = reinterpret_cast<const float4*>(x)[(p & 4095) * 32 + c];
    float4 rv = reinterpret_cast<const float4*>(rel)[((p >> 12) & 1023) * 32 + c];
    float sgn = (p & (1 << 22)) ? -1.f : 1.f;
    acc.x += sgn * (xv.x + rv.x);
    acc.y += sgn * (xv.y + rv.y);
    acc.z += sgn * (xv.z + rv.z);
    acc.w += sgn * (xv.w + rv.w);
  }
  *reinterpret_cast<float4*>(&sAcc[slot * 132 + c * 4]) = acc;
  __syncthreads();
  if (t < 128) {
    float s = 0.f;
#pragma unroll
    for (int k = 0; k < 8; ++k) s += sAcc[k * 132 + t];
    q[n * DIM + t] = f2bf(0.1f * x[n * DIM + t] + s);
  }
}

// ---------------- prep: E f32 -> bf16 row-major (scale-folded) + transposed (raw) ----
__global__ __launch_bounds__(256) void k_prep(
    const float* __restrict__ ent, const float* __restrict__ scale,
    unsigned short* __restrict__ ebf, unsigned short* __restrict__ etbf)
{
  __shared__ float sT[64 * 133];
  const int t = threadIdx.x;
  const int e0 = blockIdx.x * 64;
#pragma unroll
  for (int i = 0; i < 8; ++i) {
    int idx = i * 256 + t;        // 0..2047
    int e = idx >> 5;             // 0..63
    int c4 = idx & 31;            // float4 chunk
    float4 v = make_float4(0.f, 0.f, 0.f, 0.f);
    float sc = 0.f;
    if (e0 + e < NENT) {
      v = reinterpret_cast<const float4*>(ent)[(e0 + e) * 32 + c4];
      sc = scale[e0 + e];
    }
    *reinterpret_cast<float4*>(&sT[e * 133 + c4 * 4]) = v;  // raw for transpose
    ushort4 bq;  // scale-folded row-major copy (S-phase operand)
    bq.x = f2bf(v.x * sc); bq.y = f2bf(v.y * sc);
    bq.z = f2bf(v.z * sc); bq.w = f2bf(v.w * sc);
    *reinterpret_cast<ushort4*>(&ebf[(e0 + e) * 128 + c4 * 4]) = bq;
  }
  __syncthreads();
  const int lane = t & 63;
  const int w = t >> 6;
  const int dl = lane >> 3;
  const int el = (lane & 7) * 8;
#pragma unroll
  for (int it = 0; it < 4; ++it) {
    int d = it * 32 + w * 8 + dl;
    ushort8 buf;
#pragma unroll
    for (int j = 0; j < 8; ++j) buf[j] = f2bf(sT[(el + j) * 133 + d]);
    *reinterpret_cast<ushort8*>(&etbf[d * NENTP + e0 + el]) = buf;
  }
}

// ---------------- fused relu-"attention", v5 ----------------------------------------
// Lesson v4: 64q/wave reuse at 1 wave/SIMD realizes only 25% MfmaUtil (no latency
// hiding). v5 keeps the reuse but restores 2 waves/SIMD by e-splitting across wave
// pairs: 8 waves = (wq 0..3) x (h 0..1). Each wave: S^T for its OWN 32-e half
// (A-frag reused over 2 tq), in-register relu+repack (half of v4's), O[64q][128d]
// accumulated over its 32-e slice (B-frag reused over 2 tq). h-partials merge via the
// existing atomic epilogue. Regs ~240 < 256 => no spill at 2 waves/SIMD.
// Per CU per tile: 256 MFMA (2066 cyc) vs 128 LDS reads (1536 cyc) -> MFMA-bound.

__device__ __forceinline__ void gll16(const void* g, void* l) {
  __builtin_amdgcn_global_load_lds(
      (const __attribute__((address_space(1))) unsigned int*)g,
      (__attribute__((address_space(3))) unsigned int*)l, 16, 0, 0);
}

__device__ __forceinline__ unsigned cvtpk(float lo, float hi) {
  unsigned r;
  asm("v_cvt_pk_bf16_f32 %0, %1, %2" : "=v"(r) : "v"(lo), "v"(hi));
  return r;
}

__global__ __launch_bounds__(512, 2) void k_flash(
    const unsigned short* __restrict__ qg,     // [4096][128] bf16
    const unsigned short* __restrict__ ebf,    // [50048][128] bf16, scale-folded
    const unsigned short* __restrict__ etbf,   // [128][50048] bf16, raw
    const float* __restrict__ bias,            // [50000] f32
    float* __restrict__ out)                   // [4096][128] f32 accum
{
  __shared__ __align__(16) unsigned short sE[2][64 * 128];   // [e][k] swizzled
  __shared__ __align__(16) unsigned short sET[2][128 * 64];  // [d][e] swizzled
  __shared__ __align__(16) float sBias[2][64];

  const int t = threadIdx.x;
  const int w = t >> 6;          // wave 0..7
  const int wq = w >> 1;         // q sub-block (64 rows)
  const int h = w & 1;           // e-half (32 rows of the 64-e tile)
  const int lane = t & 63;
  const int l31 = lane & 31;
  const int hi = lane >> 5;

  const int m0 = blockIdx.x * 256;
  const int tile_lo = (blockIdx.y * NTILES) / NSPLIT;
  const int tile_hi = ((blockIdx.y + 1) * NTILES) / NSPLIT;

  // staging source swizzle (loop-invariant). LDS dest is linear (lane*16 per HW);
  // source column is XOR'd so that read-side XOR recovers logical layout.
  const int cE = (((t & 15) ^ ((t >> 4) & 15))) * 8;  // shorts, into ebf row
  const int rE = t >> 4;                              // 0..31; + i*32 -> e row
  const int cT = (((t & 7) ^ ((t >> 3) & 7))) * 8;    // shorts, into etbf row slice
  const int rT = t >> 3;                              // 0..63; + i*64 -> d row

  // ---- Q fragments, straight from global (rows m0 + wq*64 + tq*32 + l31) ----
  short8 qf[2][8];
#pragma unroll
  for (int tq = 0; tq < 2; ++tq) {
    const unsigned short* qrow =
        qg + (size_t)(m0 + wq * 64 + tq * 32 + l31) * DIM + hi * 8;
#pragma unroll
    for (int kk = 0; kk < 8; ++kk)
      qf[tq][kk] = *reinterpret_cast<const short8*>(qrow + kk * 16);
  }

  f32x16 accO[2][4];
#pragma unroll
  for (int tq = 0; tq < 2; ++tq)
#pragma unroll
    for (int td = 0; td < 4; ++td)
#pragma unroll
      for (int r = 0; r < 16; ++r) accO[tq][td][r] = 0.f;

  // ---- prologue: stage first tile into buf 0 ----
  {
    const int vt = tile_lo * 64;
#pragma unroll
    for (int i = 0; i < 2; ++i) {
      gll16(ebf + (size_t)(vt + i * 32 + rE) * DIM + cE, &sE[0][i * 4096 + w * 512]);
      gll16(etbf + (size_t)(i * 64 + rT) * NENTP + vt + cT, &sET[0][i * 4096 + w * 512]);
    }
    if (t < 64) sBias[0][t] = (vt + t < NENT) ? bias[vt + t] : 0.f;
  }
  __syncthreads();

  int cur = 0;
  for (int tile = tile_lo; tile < tile_hi; ++tile) {
    // ---- issue next-tile stage into cur^1 (overlaps with whole tile compute) ----
    if (tile + 1 < tile_hi) {
      const int vt = (tile + 1) * 64;
#pragma unroll
      for (int i = 0; i < 2; ++i) {
        gll16(ebf + (size_t)(vt + i * 32 + rE) * DIM + cE, &sE[cur ^ 1][i * 4096 + w * 512]);
        gll16(etbf + (size_t)(i * 64 + rT) * NENTP + vt + cT, &sET[cur ^ 1][i * 4096 + w * 512]);
      }
      if (t < 64) sBias[cur ^ 1][t] = (vt + t < NENT) ? bias[vt + t] : 0.f;
    }

    // ---- S^T = Etile[own 32e] @ Q^T : A-frag reused across 2 tq ----
    // accST[tq] reg r holds S^T[e = h*32 + (r&3)+8*(r>>2)+4*hi][q = tq*32 + l31]
    const unsigned short* sEc = sE[cur];
    const float* sb = sBias[cur];
    f32x16 accST[2];
#pragma unroll
    for (int tq = 0; tq < 2; ++tq)
#pragma unroll
      for (int r = 0; r < 16; ++r) accST[tq][r] = 0.f;

    __builtin_amdgcn_s_setprio(1);
#pragma unroll
    for (int kk = 0; kk < 8; ++kk) {
      const int col = ((kk * 2 + hi) ^ (l31 & 15)) * 8;   // swizzled 16B chunk
      short8 a = *reinterpret_cast<const short8*>(
          &sEc[(h * 32 + l31) * 128 + col]);
      accST[0] = __builtin_amdgcn_mfma_f32_32x32x16_bf16(a, qf[0][kk], accST[0], 0, 0, 0);
      accST[1] = __builtin_amdgcn_mfma_f32_32x32x16_bf16(a, qf[1][kk], accST[1], 0, 0, 0);
    }
    __builtin_amdgcn_s_setprio(0);

    // ---- P = relu(S^T + bias); repack own 32-e half to O-phase A-frags ----
    short8 F[2][2];  // F[tq][ke]: P[q = tq*32 + l31][e = h*32 + ke*16 + hi*8 + j]
#pragma unroll
    for (int tq = 0; tq < 2; ++tq) {
      float p[16];
#pragma unroll
      for (int g = 0; g < 4; ++g) {
        f32x4 b4 = *reinterpret_cast<const f32x4*>(&sb[h * 32 + g * 8 + hi * 4]);
#pragma unroll
        for (int j = 0; j < 4; ++j)
          p[g * 4 + j] = fmaxf(accST[tq][g * 4 + j] + b4[j], 0.f);
      }
      unsigned wr[8];
#pragma unroll
      for (int c2 = 0; c2 < 8; ++c2) wr[c2] = cvtpk(p[2 * c2], p[2 * c2 + 1]);
      uint2v r02 = __builtin_amdgcn_permlane32_swap(wr[0], wr[2], false, false);
      uint2v r13 = __builtin_amdgcn_permlane32_swap(wr[1], wr[3], false, false);
      uint2v r46 = __builtin_amdgcn_permlane32_swap(wr[4], wr[6], false, false);
      uint2v r57 = __builtin_amdgcn_permlane32_swap(wr[5], wr[7], false, false);
      union { unsigned u[4]; short8 s; } f0, f1;
      f0.u[0] = r02[0]; f0.u[1] = r13[0]; f0.u[2] = r02[1]; f0.u[3] = r13[1];
      f1.u[0] = r46[0]; f1.u[1] = r57[0]; f1.u[2] = r46[1]; f1.u[3] = r57[1];
      F[tq][0] = f0.s;
      F[tq][1] = f1.s;
    }

    // ---- O += P[own 32e] @ Etile[own 32e] : B-frag reused across 2 tq ----
    const unsigned short* sTc = sET[cur];
    __builtin_amdgcn_s_setprio(1);
#pragma unroll
    for (int ke = 0; ke < 2; ++ke) {
      const int col = ((h * 4 + ke * 2 + hi) ^ (l31 & 7)) * 8;  // swizzled 16B chunk
#pragma unroll
      for (int td = 0; td < 4; ++td) {
        const int d = td * 32 + l31;
        short8 bT = *reinterpret_cast<const short8*>(&sTc[d * 64 + col]);
        accO[0][td] = __builtin_amdgcn_mfma_f32_32x32x16_bf16(F[0][ke], bT, accO[0][td], 0, 0, 0);
        accO[1][td] = __builtin_amdgcn_mfma_f32_32x32x16_bf16(F[1][ke], bT, accO[1][td], 0, 0, 0);
      }
    }
    __builtin_amdgcn_s_setprio(0);

    __syncthreads();   // drains vmcnt (prefetch landed) + lgkm; swap buffers
    cur ^= 1;
  }

  // ---- epilogue: atomic accumulate partial O (both e-halves merge here) ----
#pragma unroll
  for (int tq = 0; tq < 2; ++tq) {
#pragma unroll
    for (int td = 0; td < 4; ++td) {
#pragma unroll
      for (int r = 0; r < 16; ++r) {
        int qrow = (r & 3) + 8 * (r >> 2) + 4 * hi;
        int row = m0 + wq * 64 + tq * 32 + qrow;
        int col = td * 32 + l31;
        atomicAdd(&out[(size_t)row * DIM + col], accO[tq][td][r]);
      }
    }
  }
}

extern "C" void kernel_launch(void* const* d_in, const int* in_sizes, int n_in,
                              void* d_out, int out_size, void* d_ws, size_t ws_size,
                              hipStream_t stream) {
  const float* x     = (const float*)d_in[0];
  const int*   ei    = (const int*)d_in[1];
  const int*   rid   = (const int*)d_in[2];
  const int*   nf    = (const int*)d_in[3];
  const float* rel   = (const float*)d_in[4];
  const float* ent   = (const float*)d_in[5];
  const float* scale = (const float*)d_in[6];
  const float* bias  = (const float*)d_in[7];
  float* out = (float*)d_out;

  // workspace layout (~28.4 MB)
  char* ws = (char*)d_ws;
  int*            cnt    = (int*)(ws + 0);                 // 16 KB
  int*            off    = (int*)(ws + (16u << 10));       // 16.4 KB
  int*            cur    = (int*)(ws + (36u << 10));       // 16 KB
  int*            sorted = (int*)(ws + (64u << 10));       // 1 MB
  unsigned short* qb     = (unsigned short*)(ws + (1344u << 10)); // 1 MB
  unsigned short* ebf    = (unsigned short*)(ws + (2560u << 10)); // 12.81 MB
  unsigned short* etbf   = (unsigned short*)(ws + (2560u << 10) + (size_t)NENTP * DIM * 2);

  hipMemsetAsync(cnt, 0, 4096 * sizeof(int), stream);
  hipMemsetAsync(d_out, 0, (size_t)out_size * sizeof(float), stream);
  k_prep<<<NTILES, 256, 0, stream>>>(ent, scale, ebf, etbf);
  k_hist<<<NEDGES / 256, 256, 0, stream>>>(ei, cnt);
  k_scan<<<1, 1024, 0, stream>>>(cnt, off, cur);
  k_place<<<NEDGES / 256, 256, 0, stream>>>(ei, rid, nf, cur, sorted);
  k_aggr<<<NNODES, 256, 0, stream>>>(off, sorted, x, rel, qb);
  k_flash<<<dim3(NNODES / 256, NSPLIT), 512, 0, stream>>>(qb, ebf, etbf, bias, out);
}

// Round 5
// 294.844 us; speedup vs baseline: 1.1122x; 1.1122x over previous
//
#include <hip/hip_runtime.h>
#include <stdint.h>

typedef __attribute__((ext_vector_type(8))) short short8;
typedef __attribute__((ext_vector_type(8))) unsigned short ushort8;
typedef __attribute__((ext_vector_type(4))) float f32x4;
typedef __attribute__((ext_vector_type(16))) float f32x16;
typedef __attribute__((ext_vector_type(2))) unsigned int uint2v;

#define NNODES 4096
#define NEDGES 262144
#define DIM 128
#define NENT 50000
#define NENTP 50048  // padded to 782*64
#define NTILES 782   // ceil(50000/64)
#define NSPLIT 16    // y-splits; 32 x-blocks * 16 = 512 blocks = 2/CU (2 waves/SIMD)

__device__ __forceinline__ unsigned short f2bf(float f) {
  union { __bf16 b; unsigned short u; } c;
  c.b = (__bf16)f;   // RNE; gfx950 has HW bf16 cvt
  return c.u;
}

// ---------------- scatter pipeline: hist -> scan -> place -> aggregate ----------------
__global__ __launch_bounds__(256) void k_hist(
    const int* __restrict__ ei, int* __restrict__ cnt)
{
  int e = blockIdx.x * 256 + threadIdx.x;
  atomicAdd(&cnt[ei[NEDGES + e]], 1);
}

__global__ __launch_bounds__(1024) void k_scan(
    const int* __restrict__ cnt, int* __restrict__ off, int* __restrict__ cur)
{
  __shared__ int s[1024];
  int t = threadIdx.x;
  int4 v = reinterpret_cast<const int4*>(cnt)[t];
  int lsum = v.x + v.y + v.z + v.w;
  s[t] = lsum; __syncthreads();
  for (int d = 1; d < 1024; d <<= 1) {
    int a = (t >= d) ? s[t - d] : 0;
    __syncthreads();
    s[t] += a;
    __syncthreads();
  }
  int base = s[t] - lsum;  // exclusive prefix
  int4 o; o.x = base; o.y = base + v.x; o.z = o.y + v.y; o.w = o.z + v.z;
  reinterpret_cast<int4*>(off)[t] = o;
  reinterpret_cast<int4*>(cur)[t] = o;
  if (t == 1023) off[4096] = base + lsum;
}

__global__ __launch_bounds__(256) void k_place(
    const int* __restrict__ ei, const int* __restrict__ rid,
    const int* __restrict__ nf, int* __restrict__ cur, int* __restrict__ sorted)
{
  int e = blockIdx.x * 256 + threadIdx.x;
  int dst = ei[NEDGES + e];
  int pos = atomicAdd(&cur[dst], 1);
  sorted[pos] = ei[e] | (rid[e] << 12) | (nf[e] << 22);
}

// one node per block; 8 edge-slots x 32 float4-lanes (8 edges in flight, 16B gathers)
// fuses buildq: q = bf16(0.1*x + aggr)
__global__ __launch_bounds__(256) void k_aggr(
    const int* __restrict__ off, const int* __restrict__ sorted,
    const float* __restrict__ x, const float* __restrict__ rel,
    unsigned short* __restrict__ q)
{
  __shared__ float sAcc[8 * 132];   // slot-major, pad 132 -> conflict-free
  const int n = blockIdx.x;
  const int t = threadIdx.x;
  const int slot = t >> 5;          // 0..7
  const int c = t & 31;             // float4 chunk (dims 4c..4c+3)
  const int b = off[n], eN = off[n + 1];
  float4 acc = make_float4(0.f, 0.f, 0.f, 0.f);
  for (int i = b + slot; i < eN; i += 8) {
    int p = sorted[i];
    float4 xv = reinterpret_cast<const float4*>(x)[(p & 4095) * 32 + c];
    float4 rv = reinterpret_cast<const float4*>(rel)[((p >> 12) & 1023) * 32 + c];
    float sgn = (p & (1 << 22)) ? -1.f : 1.f;
    acc.x += sgn * (xv.x + rv.x);
    acc.y += sgn * (xv.y + rv.y);
    acc.z += sgn * (xv.z + rv.z);
    acc.w += sgn * (xv.w + rv.w);
  }
  *reinterpret_cast<float4*>(&sAcc[slot * 132 + c * 4]) = acc;
  __syncthreads();
  if (t < 128) {
    float s = 0.f;
#pragma unroll
    for (int k = 0; k < 8; ++k) s += sAcc[k * 132 + t];
    q[n * DIM + t] = f2bf(0.1f * x[n * DIM + t] + s);
  }
}

// ---------------- prep: E f32 -> bf16 row-major (scale-folded) + transposed (raw) ----
__global__ __launch_bounds__(256) void k_prep(
    const float* __restrict__ ent, const float* __restrict__ scale,
    unsigned short* __restrict__ ebf, unsigned short* __restrict__ etbf)
{
  __shared__ float sT[64 * 133];
  const int t = threadIdx.x;
  const int e0 = blockIdx.x * 64;
#pragma unroll
  for (int i = 0; i < 8; ++i) {
    int idx = i * 256 + t;        // 0..2047
    int e = idx >> 5;             // 0..63
    int c4 = idx & 31;            // float4 chunk
    float4 v = make_float4(0.f, 0.f, 0.f, 0.f);
    float sc = 0.f;
    if (e0 + e < NENT) {
      v = reinterpret_cast<const float4*>(ent)[(e0 + e) * 32 + c4];
      sc = scale[e0 + e];
    }
    *reinterpret_cast<float4*>(&sT[e * 133 + c4 * 4]) = v;  // raw for transpose
    ushort4 bq;  // scale-folded row-major copy (S-phase operand)
    bq.x = f2bf(v.x * sc); bq.y = f2bf(v.y * sc);
    bq.z = f2bf(v.z * sc); bq.w = f2bf(v.w * sc);
    *reinterpret_cast<ushort4*>(&ebf[(e0 + e) * 128 + c4 * 4]) = bq;
  }
  __syncthreads();
  const int lane = t & 63;
  const int w = t >> 6;
  const int dl = lane >> 3;
  const int el = (lane & 7) * 8;
#pragma unroll
  for (int it = 0; it < 4; ++it) {
    int d = it * 32 + w * 8 + dl;
    ushort8 buf;
#pragma unroll
    for (int j = 0; j < 8; ++j) buf[j] = f2bf(sT[(el + j) * 133 + d]);
    *reinterpret_cast<ushort8*>(&etbf[d * NENTP + e0 + el]) = buf;
  }
}

// ---------------- fused relu-"attention", v6 ----------------------------------------
// Lesson v5: one 512-thread block per CU -> both waves/SIMD share one barrier group ->
// whole-CU stall at every barrier + phase bunching (195us, MfmaUtil 22%). Lesson v1:
// two INDEPENDENT 256-thread blocks per CU overlap across barriers (m114) but paid
// 1.0 LDS-read/MFMA. v6 = both: 256-thread block, 4 waves = (wq 0..1) x (h 0..1),
// q-block 128. Each wave: S^T for own 32-e half (A-frag reused over 2 tq), in-reg
// relu+repack, O[64q][128d] over own 32-e slice (B-frag reused over 2 tq)
// -> 0.5 LDS-read/MFMA. h-partials merged via LDS (reusing dead sE/sET) then 1
// atomicAdd -> 16 atomics/elem. 512 blocks = 2/CU, regs ~245 < 256 (v5-verified).

__device__ __forceinline__ void gll16(const void* g, void* l) {
  __builtin_amdgcn_global_load_lds(
      (const __attribute__((address_space(1))) unsigned int*)g,
      (__attribute__((address_space(3))) unsigned int*)l, 16, 0, 0);
}

__device__ __forceinline__ unsigned cvtpk(float lo, float hi) {
  unsigned r;
  asm("v_cvt_pk_bf16_f32 %0, %1, %2" : "=v"(r) : "v"(lo), "v"(hi));
  return r;
}

__global__ __launch_bounds__(256, 2) void k_flash(
    const unsigned short* __restrict__ qg,     // [4096][128] bf16
    const unsigned short* __restrict__ ebf,    // [50048][128] bf16, scale-folded
    const unsigned short* __restrict__ etbf,   // [128][50048] bf16, raw
    const float* __restrict__ bias,            // [50000] f32
    float* __restrict__ out)                   // [4096][128] f32 accum
{
  // carved shared: main phase {sE[2][8192], sET[2][8192], sBias[2][64]} = 66048 B;
  // epilogue reuses bytes 0..65535 as mrg[2][64][128] f32 (sE/sET dead by then).
  __shared__ __align__(16) char smem[66048];
  unsigned short* sE    = (unsigned short*)smem;             // [2][64*128]
  unsigned short* sET   = (unsigned short*)(smem + 32768);   // [2][128*64]
  float*          sBias = (float*)(smem + 65536);            // [2][64]
  float*          mrg   = (float*)smem;                      // [2][64][128] epilogue

  const int t = threadIdx.x;
  const int w = t >> 6;          // wave 0..3
  const int wq = w >> 1;         // q sub-block (64 rows)
  const int h = w & 1;           // e-half (32 rows of the 64-e tile)
  const int lane = t & 63;
  const int l31 = lane & 31;
  const int hi = lane >> 5;

  const int m0 = blockIdx.x * 128;
  const int tile_lo = (blockIdx.y * NTILES) / NSPLIT;
  const int tile_hi = ((blockIdx.y + 1) * NTILES) / NSPLIT;

  // staging source swizzle (loop-invariant). LDS dest is linear (lane*16 per HW);
  // source column is XOR'd so that read-side XOR recovers logical layout.
  const int cE = (((t & 15) ^ ((t >> 4) & 15))) * 8;  // shorts, into ebf row
  const int rE = t >> 4;                              // 0..15; + i*16 -> e row
  const int cT = (((t & 7) ^ ((t >> 3) & 7))) * 8;    // shorts, into etbf row slice
  const int rT = t >> 3;                              // 0..31; + i*32 -> d row
  const int wbase = w * 512;                          // shorts; wave-uniform LDS base

  // ---- Q fragments, straight from global (rows m0 + wq*64 + tq*32 + l31) ----
  short8 qf[2][8];
#pragma unroll
  for (int tq = 0; tq < 2; ++tq) {
    const unsigned short* qrow =
        qg + (size_t)(m0 + wq * 64 + tq * 32 + l31) * DIM + hi * 8;
#pragma unroll
    for (int kk = 0; kk < 8; ++kk)
      qf[tq][kk] = *reinterpret_cast<const short8*>(qrow + kk * 16);
  }

  f32x16 accO[2][4];
#pragma unroll
  for (int tq = 0; tq < 2; ++tq)
#pragma unroll
    for (int td = 0; td < 4; ++td)
#pragma unroll
      for (int r = 0; r < 16; ++r) accO[tq][td][r] = 0.f;

  // ---- prologue: stage first tile into buf 0 ----
  {
    const int vt = tile_lo * 64;
#pragma unroll
    for (int i = 0; i < 4; ++i) {
      gll16(ebf + (size_t)(vt + i * 16 + rE) * DIM + cE, &sE[i * 2048 + wbase]);
      gll16(etbf + (size_t)(i * 32 + rT) * NENTP + vt + cT, &sET[i * 2048 + wbase]);
    }
    if (t < 64) sBias[t] = (vt + t < NENT) ? bias[vt + t] : 0.f;
  }
  __syncthreads();

  int cur = 0;
  for (int tile = tile_lo; tile < tile_hi; ++tile) {
    // ---- issue next-tile stage into cur^1 (overlaps with whole tile compute) ----
    if (tile + 1 < tile_hi) {
      const int vt = (tile + 1) * 64;
      const int b = (cur ^ 1) * 8192;
#pragma unroll
      for (int i = 0; i < 4; ++i) {
        gll16(ebf + (size_t)(vt + i * 16 + rE) * DIM + cE, &sE[b + i * 2048 + wbase]);
        gll16(etbf + (size_t)(i * 32 + rT) * NENTP + vt + cT, &sET[b + i * 2048 + wbase]);
      }
      if (t < 64) sBias[(cur ^ 1) * 64 + t] = (vt + t < NENT) ? bias[vt + t] : 0.f;
    }

    // ---- S^T = Etile[own 32e] @ Q^T : A-frag reused across 2 tq ----
    // accST[tq] reg r holds S^T[e = h*32 + (r&3)+8*(r>>2)+4*hi][q = tq*32 + l31]
    const unsigned short* sEc = sE + cur * 8192;
    const float* sb = sBias + cur * 64;
    f32x16 accST[2];
#pragma unroll
    for (int tq = 0; tq < 2; ++tq)
#pragma unroll
      for (int r = 0; r < 16; ++r) accST[tq][r] = 0.f;

    __builtin_amdgcn_s_setprio(1);
#pragma unroll
    for (int kk = 0; kk < 8; ++kk) {
      const int col = ((kk * 2 + hi) ^ (l31 & 15)) * 8;   // swizzled 16B chunk
      short8 a = *reinterpret_cast<const short8*>(
          &sEc[(h * 32 + l31) * 128 + col]);
      accST[0] = __builtin_amdgcn_mfma_f32_32x32x16_bf16(a, qf[0][kk], accST[0], 0, 0, 0);
      accST[1] = __builtin_amdgcn_mfma_f32_32x32x16_bf16(a, qf[1][kk], accST[1], 0, 0, 0);
    }
    __builtin_amdgcn_s_setprio(0);

    // ---- P = relu(S^T + bias); repack own 32-e half to O-phase A-frags ----
    short8 F[2][2];  // F[tq][ke]: P[q = tq*32 + l31][e = h*32 + ke*16 + hi*8 + j]
#pragma unroll
    for (int tq = 0; tq < 2; ++tq) {
      float p[16];
#pragma unroll
      for (int g = 0; g < 4; ++g) {
        f32x4 b4 = *reinterpret_cast<const f32x4*>(&sb[h * 32 + g * 8 + hi * 4]);
#pragma unroll
        for (int j = 0; j < 4; ++j)
          p[g * 4 + j] = fmaxf(accST[tq][g * 4 + j] + b4[j], 0.f);
      }
      unsigned wr[8];
#pragma unroll
      for (int c2 = 0; c2 < 8; ++c2) wr[c2] = cvtpk(p[2 * c2], p[2 * c2 + 1]);
      uint2v r02 = __builtin_amdgcn_permlane32_swap(wr[0], wr[2], false, false);
      uint2v r13 = __builtin_amdgcn_permlane32_swap(wr[1], wr[3], false, false);
      uint2v r46 = __builtin_amdgcn_permlane32_swap(wr[4], wr[6], false, false);
      uint2v r57 = __builtin_amdgcn_permlane32_swap(wr[5], wr[7], false, false);
      union { unsigned u[4]; short8 s; } f0, f1;
      f0.u[0] = r02[0]; f0.u[1] = r13[0]; f0.u[2] = r02[1]; f0.u[3] = r13[1];
      f1.u[0] = r46[0]; f1.u[1] = r57[0]; f1.u[2] = r46[1]; f1.u[3] = r57[1];
      F[tq][0] = f0.s;
      F[tq][1] = f1.s;
    }

    // ---- O += P[own 32e] @ Etile[own 32e] : B-frag reused across 2 tq ----
    const unsigned short* sTc = sET + cur * 8192;
    __builtin_amdgcn_s_setprio(1);
#pragma unroll
    for (int ke = 0; ke < 2; ++ke) {
      const int col = ((h * 4 + ke * 2 + hi) ^ (l31 & 7)) * 8;  // swizzled 16B chunk
#pragma unroll
      for (int td = 0; td < 4; ++td) {
        const int d = td * 32 + l31;
        short8 bT = *reinterpret_cast<const short8*>(&sTc[d * 64 + col]);
        accO[0][td] = __builtin_amdgcn_mfma_f32_32x32x16_bf16(F[0][ke], bT, accO[0][td], 0, 0, 0);
        accO[1][td] = __builtin_amdgcn_mfma_f32_32x32x16_bf16(F[1][ke], bT, accO[1][td], 0, 0, 0);
      }
    }
    __builtin_amdgcn_s_setprio(0);

    __syncthreads();   // drains vmcnt (prefetch landed) + lgkm; swap buffers
    cur ^= 1;
  }

  // ---- epilogue: merge h-halves via LDS (sE/sET dead), then 1 atomicAdd/elem ----
  if (h == 1) {
#pragma unroll
    for (int tq = 0; tq < 2; ++tq)
#pragma unroll
      for (int td = 0; td < 4; ++td)
#pragma unroll
        for (int r = 0; r < 16; ++r) {
          int qrow = (r & 3) + 8 * (r >> 2) + 4 * hi;
          mrg[(wq * 64 + tq * 32 + qrow) * 128 + td * 32 + l31] = accO[tq][td][r];
        }
  }
  __syncthreads();
  if (h == 0) {
#pragma unroll
    for (int tq = 0; tq < 2; ++tq)
#pragma unroll
      for (int td = 0; td < 4; ++td)
#pragma unroll
        for (int r = 0; r < 16; ++r) {
          int qrow = (r & 3) + 8 * (r >> 2) + 4 * hi;
          float v = accO[tq][td][r] +
                    mrg[(wq * 64 + tq * 32 + qrow) * 128 + td * 32 + l31];
          int row = m0 + wq * 64 + tq * 32 + qrow;
          int col = td * 32 + l31;
          atomicAdd(&out[(size_t)row * DIM + col], v);
        }
  }
}

extern "C" void kernel_launch(void* const* d_in, const int* in_sizes, int n_in,
                              void* d_out, int out_size, void* d_ws, size_t ws_size,
                              hipStream_t stream) {
  const float* x     = (const float*)d_in[0];
  const int*   ei    = (const int*)d_in[1];
  const int*   rid   = (const int*)d_in[2];
  const int*   nf    = (const int*)d_in[3];
  const float* rel   = (const float*)d_in[4];
  const float* ent   = (const float*)d_in[5];
  const float* scale = (const float*)d_in[6];
  const float* bias  = (const float*)d_in[7];
  float* out = (float*)d_out;

  // workspace layout (~28.4 MB)
  char* ws = (char*)d_ws;
  int*            cnt    = (int*)(ws + 0);                 // 16 KB
  int*            off    = (int*)(ws + (16u << 10));       // 16.4 KB
  int*            cur    = (int*)(ws + (36u << 10));       // 16 KB
  int*            sorted = (int*)(ws + (64u << 10));       // 1 MB
  unsigned short* qb     = (unsigned short*)(ws + (1344u << 10)); // 1 MB
  unsigned short* ebf    = (unsigned short*)(ws + (2560u << 10)); // 12.81 MB
  unsigned short* etbf   = (unsigned short*)(ws + (2560u << 10) + (size_t)NENTP * DIM * 2);

  hipMemsetAsync(cnt, 0, 4096 * sizeof(int), stream);
  hipMemsetAsync(d_out, 0, (size_t)out_size * sizeof(float), stream);
  k_prep<<<NTILES, 256, 0, stream>>>(ent, scale, ebf, etbf);
  k_hist<<<NEDGES / 256, 256, 0, stream>>>(ei, cnt);
  k_scan<<<1, 1024, 0, stream>>>(cnt, off, cur);
  k_place<<<NEDGES / 256, 256, 0, stream>>>(ei, rid, nf, cur, sorted);
  k_aggr<<<NNODES, 256, 0, stream>>>(off, sorted, x, rel, qb);
  k_flash<<<dim3(NNODES / 128, NSPLIT), 256, 0, stream>>>(qb, ebf, etbf, bias, out);
}

// Round 6
// 284.019 us; speedup vs baseline: 1.1546x; 1.0381x over previous
//
#include <hip/hip_runtime.h>
#include <stdint.h>

typedef __attribute__((ext_vector_type(8))) short short8;
typedef __attribute__((ext_vector_type(8))) unsigned short ushort8;
typedef __attribute__((ext_vector_type(4))) float f32x4;
typedef __attribute__((ext_vector_type(16))) float f32x16;
typedef __attribute__((ext_vector_type(2))) unsigned int uint2v;

#define NNODES 4096
#define NEDGES 262144
#define DIM 128
#define NENT 50000
#define NENTP 50048  // padded to 782*64 (k_prep granularity)
#define ETILE 32     // e-rows per k_flash tile
#define NT32 1563    // ceil(50000/32); rows 50000..50015 are zero-padded
#define NSPLIT 24    // y-splits; 32 x-blocks * 24 = 768 blocks = 3/CU (3 waves/SIMD)

__device__ __forceinline__ unsigned short f2bf(float f) {
  union { __bf16 b; unsigned short u; } c;
  c.b = (__bf16)f;   // RNE; gfx950 has HW bf16 cvt
  return c.u;
}

// ---------------- scatter pipeline: hist -> scan -> place -> aggregate ----------------
__global__ __launch_bounds__(256) void k_hist(
    const int* __restrict__ ei, int* __restrict__ cnt)
{
  int e = blockIdx.x * 256 + threadIdx.x;
  atomicAdd(&cnt[ei[NEDGES + e]], 1);
}

__global__ __launch_bounds__(1024) void k_scan(
    const int* __restrict__ cnt, int* __restrict__ off, int* __restrict__ cur)
{
  __shared__ int s[1024];
  int t = threadIdx.x;
  int4 v = reinterpret_cast<const int4*>(cnt)[t];
  int lsum = v.x + v.y + v.z + v.w;
  s[t] = lsum; __syncthreads();
  for (int d = 1; d < 1024; d <<= 1) {
    int a = (t >= d) ? s[t - d] : 0;
    __syncthreads();
    s[t] += a;
    __syncthreads();
  }
  int base = s[t] - lsum;  // exclusive prefix
  int4 o; o.x = base; o.y = base + v.x; o.z = o.y + v.y; o.w = o.z + v.z;
  reinterpret_cast<int4*>(off)[t] = o;
  reinterpret_cast<int4*>(cur)[t] = o;
  if (t == 1023) off[4096] = base + lsum;
}

__global__ __launch_bounds__(256) void k_place(
    const int* __restrict__ ei, const int* __restrict__ rid,
    const int* __restrict__ nf, int* __restrict__ cur, int* __restrict__ sorted)
{
  int e = blockIdx.x * 256 + threadIdx.x;
  int dst = ei[NEDGES + e];
  int pos = atomicAdd(&cur[dst], 1);
  sorted[pos] = ei[e] | (rid[e] << 12) | (nf[e] << 22);
}

// one node per block; 8 edge-slots x 32 float4-lanes (8 edges in flight, 16B gathers)
// fuses buildq: q = bf16(0.1*x + aggr)
__global__ __launch_bounds__(256) void k_aggr(
    const int* __restrict__ off, const int* __restrict__ sorted,
    const float* __restrict__ x, const float* __restrict__ rel,
    unsigned short* __restrict__ q)
{
  __shared__ float sAcc[8 * 132];   // slot-major, pad 132 -> conflict-free
  const int n = blockIdx.x;
  const int t = threadIdx.x;
  const int slot = t >> 5;          // 0..7
  const int c = t & 31;             // float4 chunk (dims 4c..4c+3)
  const int b = off[n], eN = off[n + 1];
  float4 acc = make_float4(0.f, 0.f, 0.f, 0.f);
  for (int i = b + slot; i < eN; i += 8) {
    int p = sorted[i];
    float4 xv = reinterpret_cast<const float4*>(x)[(p & 4095) * 32 + c];
    float4 rv = reinterpret_cast<const float4*>(rel)[((p >> 12) & 1023) * 32 + c];
    float sgn = (p & (1 << 22)) ? -1.f : 1.f;
    acc.x += sgn * (xv.x + rv.x);
    acc.y += sgn * (xv.y + rv.y);
    acc.z += sgn * (xv.z + rv.z);
    acc.w += sgn * (xv.w + rv.w);
  }
  *reinterpret_cast<float4*>(&sAcc[slot * 132 + c * 4]) = acc;
  __syncthreads();
  if (t < 128) {
    float s = 0.f;
#pragma unroll
    for (int k = 0; k < 8; ++k) s += sAcc[k * 132 + t];
    q[n * DIM + t] = f2bf(0.1f * x[n * DIM + t] + s);
  }
}

// ---------------- prep: E f32 -> bf16 row-major (scale-folded) + transposed (raw) ----
__global__ __launch_bounds__(256) void k_prep(
    const float* __restrict__ ent, const float* __restrict__ scale,
    unsigned short* __restrict__ ebf, unsigned short* __restrict__ etbf)
{
  __shared__ float sT[64 * 133];
  const int t = threadIdx.x;
  const int e0 = blockIdx.x * 64;
#pragma unroll
  for (int i = 0; i < 8; ++i) {
    int idx = i * 256 + t;        // 0..2047
    int e = idx >> 5;             // 0..63
    int c4 = idx & 31;            // float4 chunk
    float4 v = make_float4(0.f, 0.f, 0.f, 0.f);
    float sc = 0.f;
    if (e0 + e < NENT) {
      v = reinterpret_cast<const float4*>(ent)[(e0 + e) * 32 + c4];
      sc = scale[e0 + e];
    }
    *reinterpret_cast<float4*>(&sT[e * 133 + c4 * 4]) = v;  // raw for transpose
    ushort4 bq;  // scale-folded row-major copy (S-phase operand)
    bq.x = f2bf(v.x * sc); bq.y = f2bf(v.y * sc);
    bq.z = f2bf(v.z * sc); bq.w = f2bf(v.w * sc);
    *reinterpret_cast<ushort4*>(&ebf[(e0 + e) * 128 + c4 * 4]) = bq;
  }
  __syncthreads();
  const int lane = t & 63;
  const int w = t >> 6;
  const int dl = lane >> 3;
  const int el = (lane & 7) * 8;
#pragma unroll
  for (int it = 0; it < 4; ++it) {
    int d = it * 32 + w * 8 + dl;
    ushort8 buf;
#pragma unroll
    for (int j = 0; j < 8; ++j) buf[j] = f2bf(sT[(el + j) * 133 + d]);
    *reinterpret_cast<ushort8*>(&etbf[d * NENTP + e0 + el]) = buf;
  }
}

// ---------------- fused relu-"attention", v7 ----------------------------------------
// Diagnosis after v1..v6: no pipe >28% busy; kernel is latency-bound and LDS capacity
// (66KB/block) capped occupancy at 2 blocks/CU (2 waves/SIMD). v7 = v1's exact proven
// loop structure with ETILE 64->32: LDS 33KB/block -> 3 blocks/CU (3 waves/SIMD,
// __launch_bounds__(256,3): 170-reg cap, ~160 used). Tiles double (1563), per-tile
// serial path halves, total MFMA unchanged. One variable vs v1: occupancy 2->3.

__device__ __forceinline__ void gll16(const void* g, void* l) {
  __builtin_amdgcn_global_load_lds(
      (const __attribute__((address_space(1))) unsigned int*)g,
      (__attribute__((address_space(3))) unsigned int*)l, 16, 0, 0);
}

__device__ __forceinline__ unsigned cvtpk(float lo, float hi) {
  unsigned r;
  asm("v_cvt_pk_bf16_f32 %0, %1, %2" : "=v"(r) : "v"(lo), "v"(hi));
  return r;
}

__global__ __launch_bounds__(256, 3) void k_flash(
    const unsigned short* __restrict__ qg,     // [4096][128] bf16
    const unsigned short* __restrict__ ebf,    // [50048][128] bf16, scale-folded
    const unsigned short* __restrict__ etbf,   // [128][50048] bf16, raw
    const float* __restrict__ bias,            // [50000] f32
    float* __restrict__ out)                   // [4096][128] f32 accum
{
  __shared__ __align__(16) unsigned short sE[2][ETILE * 128];   // [e][k] swizzled
  __shared__ __align__(16) unsigned short sET[2][128 * ETILE];  // [d][e] swizzled
  __shared__ __align__(16) float sBias[2][ETILE];

  const int t = threadIdx.x;
  const int w = t >> 6;          // wave 0..3 (= 32-row q sub-block)
  const int lane = t & 63;
  const int l31 = lane & 31;
  const int hi = lane >> 5;

  const int m0 = blockIdx.x * 128;
  const int tile_lo = (blockIdx.y * NT32) / NSPLIT;
  const int tile_hi = ((blockIdx.y + 1) * NT32) / NSPLIT;

  // staging source swizzle (loop-invariant). LDS dest is linear (lane*16 per HW);
  // source column is XOR'd so that read-side XOR recovers logical layout.
  // sE rows are 128 shorts (16 chunks, key row&15); sET rows 32 shorts (4 chunks,
  // key row&3).
  const int cE = (((t & 15) ^ ((t >> 4) & 15))) * 8;  // shorts, into ebf row
  const int rE = t >> 4;                              // 0..15; + i*16 -> e row
  const int cT = (((t & 3) ^ ((t >> 2) & 3))) * 8;    // shorts, into etbf row slice
  const int rT = t >> 2;                              // 0..63; + i*64 -> d row

  // ---- Q fragments, straight from global (rows m0 + w*32 + l31) ----
  short8 qf[8];
  {
    const unsigned short* qrow = qg + (size_t)(m0 + w * 32 + l31) * DIM + hi * 8;
#pragma unroll
    for (int kk = 0; kk < 8; ++kk)
      qf[kk] = *reinterpret_cast<const short8*>(qrow + kk * 16);
  }

  f32x16 accO[4];
#pragma unroll
  for (int td = 0; td < 4; ++td)
#pragma unroll
    for (int r = 0; r < 16; ++r) accO[td][r] = 0.f;

  // ---- prologue: stage first tile into buf 0 ----
  {
    const int vt = tile_lo * ETILE;
#pragma unroll
    for (int i = 0; i < 2; ++i)
      gll16(ebf + (size_t)(vt + i * 16 + rE) * DIM + cE, &sE[0][(i * 256 + t) * 8]);
#pragma unroll
    for (int i = 0; i < 2; ++i)
      gll16(etbf + (size_t)(i * 64 + rT) * NENTP + vt + cT, &sET[0][(i * 256 + t) * 8]);
    if (t < ETILE) sBias[0][t] = (vt + t < NENT) ? bias[vt + t] : 0.f;
  }
  __syncthreads();

  int cur = 0;
  for (int tile = tile_lo; tile < tile_hi; ++tile) {
    // ---- issue next-tile stage into cur^1 (overlaps with whole tile compute) ----
    if (tile + 1 < tile_hi) {
      const int vt = (tile + 1) * ETILE;
#pragma unroll
      for (int i = 0; i < 2; ++i)
        gll16(ebf + (size_t)(vt + i * 16 + rE) * DIM + cE,
              &sE[cur ^ 1][(i * 256 + t) * 8]);
#pragma unroll
      for (int i = 0; i < 2; ++i)
        gll16(etbf + (size_t)(i * 64 + rT) * NENTP + vt + cT,
              &sET[cur ^ 1][(i * 256 + t) * 8]);
      if (t < ETILE) sBias[cur ^ 1][t] = (vt + t < NENT) ? bias[vt + t] : 0.f;
    }

    // ---- S^T = Etile_scaled @ Q^T : wave computes S^T[32e][32q] ----
    // accST reg r holds S^T[e = (r&3)+8*(r>>2)+4*hi][q = l31]
    const unsigned short* sEc = sE[cur];
    const float* sb = sBias[cur];
    f32x16 accST;
#pragma unroll
    for (int r = 0; r < 16; ++r) accST[r] = 0.f;

    __builtin_amdgcn_s_setprio(1);
#pragma unroll
    for (int kk = 0; kk < 8; ++kk) {
      const int col = ((kk * 2 + hi) ^ (l31 & 15)) * 8;   // swizzled 16B chunk
      short8 a = *reinterpret_cast<const short8*>(&sEc[l31 * 128 + col]);
      accST = __builtin_amdgcn_mfma_f32_32x32x16_bf16(a, qf[kk], accST, 0, 0, 0);
    }
    __builtin_amdgcn_s_setprio(0);

    // ---- P = relu(S^T + bias); repack in-register to O-phase A-frags ----
    short8 F[2];  // F[ke]: P[q = l31][e = ke*16 + hi*8 + j]
    {
      float p[16];
#pragma unroll
      for (int g = 0; g < 4; ++g) {
        f32x4 b4 = *reinterpret_cast<const f32x4*>(&sb[g * 8 + hi * 4]);
#pragma unroll
        for (int j = 0; j < 4; ++j)
          p[g * 4 + j] = fmaxf(accST[g * 4 + j] + b4[j], 0.f);
      }
      unsigned wr[8];
#pragma unroll
      for (int c2 = 0; c2 < 8; ++c2) wr[c2] = cvtpk(p[2 * c2], p[2 * c2 + 1]);
      uint2v r02 = __builtin_amdgcn_permlane32_swap(wr[0], wr[2], false, false);
      uint2v r13 = __builtin_amdgcn_permlane32_swap(wr[1], wr[3], false, false);
      uint2v r46 = __builtin_amdgcn_permlane32_swap(wr[4], wr[6], false, false);
      uint2v r57 = __builtin_amdgcn_permlane32_swap(wr[5], wr[7], false, false);
      union { unsigned u[4]; short8 s; } f0, f1;
      f0.u[0] = r02[0]; f0.u[1] = r13[0]; f0.u[2] = r02[1]; f0.u[3] = r13[1];
      f1.u[0] = r46[0]; f1.u[1] = r57[0]; f1.u[2] = r46[1]; f1.u[3] = r57[1];
      F[0] = f0.s;
      F[1] = f1.s;
    }

    // ---- O += P @ Etile : wave computes O[32q][128d] ----
    const unsigned short* sTc = sET[cur];
    __builtin_amdgcn_s_setprio(1);
#pragma unroll
    for (int ke = 0; ke < 2; ++ke) {
      const int col0 = (ke * 2 + hi);
#pragma unroll
      for (int td = 0; td < 4; ++td) {
        const int d = td * 32 + l31;
        const int col = (col0 ^ (l31 & 3)) * 8;  // swizzled 16B chunk (key d&3=l31&3)
        short8 bT = *reinterpret_cast<const short8*>(&sTc[d * ETILE + col]);
        accO[td] = __builtin_amdgcn_mfma_f32_32x32x16_bf16(F[ke], bT, accO[td], 0, 0, 0);
      }
    }
    __builtin_amdgcn_s_setprio(0);

    __syncthreads();   // drains vmcnt (prefetch landed) + lgkm; swap buffers
    cur ^= 1;
  }

  // ---- epilogue: atomic accumulate partial O into f32 output ----
#pragma unroll
  for (int td = 0; td < 4; ++td) {
#pragma unroll
    for (int r = 0; r < 16; ++r) {
      int qrow = (r & 3) + 8 * (r >> 2) + 4 * hi;
      int row = m0 + w * 32 + qrow;
      int col = td * 32 + l31;
      atomicAdd(&out[(size_t)row * DIM + col], accO[td][r]);
    }
  }
}

extern "C" void kernel_launch(void* const* d_in, const int* in_sizes, int n_in,
                              void* d_out, int out_size, void* d_ws, size_t ws_size,
                              hipStream_t stream) {
  const float* x     = (const float*)d_in[0];
  const int*   ei    = (const int*)d_in[1];
  const int*   rid   = (const int*)d_in[2];
  const int*   nf    = (const int*)d_in[3];
  const float* rel   = (const float*)d_in[4];
  const float* ent   = (const float*)d_in[5];
  const float* scale = (const float*)d_in[6];
  const float* bias  = (const float*)d_in[7];
  float* out = (float*)d_out;

  // workspace layout (~28.4 MB)
  char* ws = (char*)d_ws;
  int*            cnt    = (int*)(ws + 0);                 // 16 KB
  int*            off    = (int*)(ws + (16u << 10));       // 16.4 KB
  int*            cur    = (int*)(ws + (36u << 10));       // 16 KB
  int*            sorted = (int*)(ws + (64u << 10));       // 1 MB
  unsigned short* qb     = (unsigned short*)(ws + (1344u << 10)); // 1 MB
  unsigned short* ebf    = (unsigned short*)(ws + (2560u << 10)); // 12.81 MB
  unsigned short* etbf   = (unsigned short*)(ws + (2560u << 10) + (size_t)NENTP * DIM * 2);

  hipMemsetAsync(cnt, 0, 4096 * sizeof(int), stream);
  hipMemsetAsync(d_out, 0, (size_t)out_size * sizeof(float), stream);
  k_prep<<<NENTP / 64, 256, 0, stream>>>(ent, scale, ebf, etbf);
  k_hist<<<NEDGES / 256, 256, 0, stream>>>(ei, cnt);
  k_scan<<<1, 1024, 0, stream>>>(cnt, off, cur);
  k_place<<<NEDGES / 256, 256, 0, stream>>>(ei, rid, nf, cur, sorted);
  k_aggr<<<NNODES, 256, 0, stream>>>(off, sorted, x, rel, qb);
  k_flash<<<dim3(NNODES / 128, NSPLIT), 256, 0, stream>>>(qb, ebf, etbf, bias, out);
}

// Round 7
// 270.011 us; speedup vs baseline: 1.2145x; 1.0519x over previous
//
#include <hip/hip_runtime.h>
#include <stdint.h>

typedef __attribute__((ext_vector_type(8))) short short8;
typedef __attribute__((ext_vector_type(8))) unsigned short ushort8;
typedef __attribute__((ext_vector_type(4))) float f32x4;
typedef __attribute__((ext_vector_type(16))) float f32x16;
typedef __attribute__((ext_vector_type(2))) unsigned int uint2v;

#define NNODES 4096
#define NEDGES 262144
#define DIM 128
#define NENT 50000
#define NENTP 50048  // padded to 782*64 (k_prep granularity)
#define PREPB 782    // NENTP/64 prep blocks
#define ETILE 32     // e-rows per k_flash tile
#define NT32 1563    // ceil(50000/32); rows 50000..50015 are zero-padded
#define NSPLIT 24    // y-splits; 32 x-blocks * 24 = 768 blocks = 3/CU (3 waves/SIMD)

__device__ __forceinline__ unsigned short f2bf(float f) {
  union { __bf16 b; unsigned short u; } c;
  c.b = (__bf16)f;   // RNE; gfx950 has HW bf16 cvt
  return c.u;
}

// ---------------- scatter pipeline: (hist fused into prep) -> scan -> place -> aggr --
__global__ __launch_bounds__(1024) void k_scan(
    const int* __restrict__ cnt, int* __restrict__ off, int* __restrict__ cur)
{
  __shared__ int s[1024];
  int t = threadIdx.x;
  int4 v = reinterpret_cast<const int4*>(cnt)[t];
  int lsum = v.x + v.y + v.z + v.w;
  s[t] = lsum; __syncthreads();
  for (int d = 1; d < 1024; d <<= 1) {
    int a = (t >= d) ? s[t - d] : 0;
    __syncthreads();
    s[t] += a;
    __syncthreads();
  }
  int base = s[t] - lsum;  // exclusive prefix
  int4 o; o.x = base; o.y = base + v.x; o.z = o.y + v.y; o.w = o.z + v.z;
  reinterpret_cast<int4*>(off)[t] = o;
  reinterpret_cast<int4*>(cur)[t] = o;
  if (t == 1023) off[4096] = base + lsum;
}

__global__ __launch_bounds__(256) void k_place(
    const int* __restrict__ ei, const int* __restrict__ rid,
    const int* __restrict__ nf, int* __restrict__ cur, int* __restrict__ sorted)
{
  int e = blockIdx.x * 256 + threadIdx.x;
  int dst = ei[NEDGES + e];
  int pos = atomicAdd(&cur[dst], 1);
  sorted[pos] = ei[e] | (rid[e] << 12) | (nf[e] << 22);
}

// one node per block; 8 edge-slots x 32 float4-lanes (8 edges in flight, 16B gathers)
// fuses buildq: q = bf16(0.1*x + aggr)
__global__ __launch_bounds__(256) void k_aggr(
    const int* __restrict__ off, const int* __restrict__ sorted,
    const float* __restrict__ x, const float* __restrict__ rel,
    unsigned short* __restrict__ q)
{
  __shared__ float sAcc[8 * 132];   // slot-major, pad 132 -> conflict-free
  const int n = blockIdx.x;
  const int t = threadIdx.x;
  const int slot = t >> 5;          // 0..7
  const int c = t & 31;             // float4 chunk (dims 4c..4c+3)
  const int b = off[n], eN = off[n + 1];
  float4 acc = make_float4(0.f, 0.f, 0.f, 0.f);
  for (int i = b + slot; i < eN; i += 8) {
    int p = sorted[i];
    float4 xv = reinterpret_cast<const float4*>(x)[(p & 4095) * 32 + c];
    float4 rv = reinterpret_cast<const float4*>(rel)[((p >> 12) & 1023) * 32 + c];
    float sgn = (p & (1 << 22)) ? -1.f : 1.f;
    acc.x += sgn * (xv.x + rv.x);
    acc.y += sgn * (xv.y + rv.y);
    acc.z += sgn * (xv.z + rv.z);
    acc.w += sgn * (xv.w + rv.w);
  }
  *reinterpret_cast<float4*>(&sAcc[slot * 132 + c * 4]) = acc;
  __syncthreads();
  if (t < 128) {
    float s = 0.f;
#pragma unroll
    for (int k = 0; k < 8; ++k) s += sAcc[k * 132 + t];
    q[n * DIM + t] = f2bf(0.1f * x[n * DIM + t] + s);
  }
}

// ---------------- prep (+ fused edge-histogram): E f32 -> bf16 row/col copies --------
// blocks [0,782): E conversion; blocks [782, 782+1024): edge-dst histogram (runs
// concurrently -> hides k_hist's latency under prep's memory time, one less launch).
__global__ __launch_bounds__(256) void k_prep(
    const float* __restrict__ ent, const float* __restrict__ scale,
    unsigned short* __restrict__ ebf, unsigned short* __restrict__ etbf,
    const int* __restrict__ ei, int* __restrict__ cnt)
{
  if (blockIdx.x >= PREPB) {
    int e = (blockIdx.x - PREPB) * 256 + threadIdx.x;
    atomicAdd(&cnt[ei[NEDGES + e]], 1);
    return;
  }
  __shared__ float sT[64 * 133];
  const int t = threadIdx.x;
  const int e0 = blockIdx.x * 64;
#pragma unroll
  for (int i = 0; i < 8; ++i) {
    int idx = i * 256 + t;        // 0..2047
    int e = idx >> 5;             // 0..63
    int c4 = idx & 31;            // float4 chunk
    float4 v = make_float4(0.f, 0.f, 0.f, 0.f);
    float sc = 0.f;
    if (e0 + e < NENT) {
      v = reinterpret_cast<const float4*>(ent)[(e0 + e) * 32 + c4];
      sc = scale[e0 + e];
    }
    *reinterpret_cast<float4*>(&sT[e * 133 + c4 * 4]) = v;  // raw for transpose
    ushort4 bq;  // scale-folded row-major copy (S-phase operand)
    bq.x = f2bf(v.x * sc); bq.y = f2bf(v.y * sc);
    bq.z = f2bf(v.z * sc); bq.w = f2bf(v.w * sc);
    *reinterpret_cast<ushort4*>(&ebf[(e0 + e) * 128 + c4 * 4]) = bq;
  }
  __syncthreads();
  const int lane = t & 63;
  const int w = t >> 6;
  const int dl = lane >> 3;
  const int el = (lane & 7) * 8;
#pragma unroll
  for (int it = 0; it < 4; ++it) {
    int d = it * 32 + w * 8 + dl;
    ushort8 buf;
#pragma unroll
    for (int j = 0; j < 8; ++j) buf[j] = f2bf(sT[(el + j) * 133 + d]);
    *reinterpret_cast<ushort8*>(&etbf[d * NENTP + e0 + el]) = buf;
  }
}

// ---------------- fused relu-"attention", v8 ----------------------------------------
// v7 regression isolated: O-phase swizzle key (d&3) collapses with lane parity ->
// only 4 of 8 bank positions used -> 8-way conflict (SQ_LDS_BANK_CONFLICT 1.92e7,
// ~27us). v8 key = (d>>2)&3 (independent of parity) -> 8 positions x 4 lanes =
// conflict floor. Also: S-phase accumulator split into even/odd-kk chains (accA/accB,
// summed in relu epilogue) -> 2-way MFMA ILP, +16 AGPR (fits 170-cap).

__device__ __forceinline__ void gll16(const void* g, void* l) {
  __builtin_amdgcn_global_load_lds(
      (const __attribute__((address_space(1))) unsigned int*)g,
      (__attribute__((address_space(3))) unsigned int*)l, 16, 0, 0);
}

__device__ __forceinline__ unsigned cvtpk(float lo, float hi) {
  unsigned r;
  asm("v_cvt_pk_bf16_f32 %0, %1, %2" : "=v"(r) : "v"(lo), "v"(hi));
  return r;
}

__global__ __launch_bounds__(256, 3) void k_flash(
    const unsigned short* __restrict__ qg,     // [4096][128] bf16
    const unsigned short* __restrict__ ebf,    // [50048][128] bf16, scale-folded
    const unsigned short* __restrict__ etbf,   // [128][50048] bf16, raw
    const float* __restrict__ bias,            // [50000] f32
    float* __restrict__ out)                   // [4096][128] f32 accum
{
  __shared__ __align__(16) unsigned short sE[2][ETILE * 128];   // [e][k] swizzled
  __shared__ __align__(16) unsigned short sET[2][128 * ETILE];  // [d][e] swizzled
  __shared__ __align__(16) float sBias[2][ETILE];

  const int t = threadIdx.x;
  const int w = t >> 6;          // wave 0..3 (= 32-row q sub-block)
  const int lane = t & 63;
  const int l31 = lane & 31;
  const int hi = lane >> 5;

  const int m0 = blockIdx.x * 128;
  const int tile_lo = (blockIdx.y * NT32) / NSPLIT;
  const int tile_hi = ((blockIdx.y + 1) * NT32) / NSPLIT;

  // staging source swizzle (loop-invariant). LDS dest is linear (lane*16 per HW);
  // source column is XOR'd so that read-side XOR recovers logical layout.
  // sE: 128-short rows, 16 chunks, key = row&15 (row = t>>4 + i*16).
  // sET: 32-short rows, 4 chunks, key = (row>>2)&3 (row = t>>2 + i*64) -> (t>>4)&3;
  //      key independent of lane parity => 8 bank positions x 4 lanes (v7 had 4x8).
  const int cE = (((t & 15) ^ ((t >> 4) & 15))) * 8;  // shorts, into ebf row
  const int rE = t >> 4;                              // 0..15; + i*16 -> e row
  const int cT = (((t & 3) ^ ((t >> 4) & 3))) * 8;    // shorts, into etbf row slice
  const int rT = t >> 2;                              // 0..63; + i*64 -> d row

  // ---- Q fragments, straight from global (rows m0 + w*32 + l31) ----
  short8 qf[8];
  {
    const unsigned short* qrow = qg + (size_t)(m0 + w * 32 + l31) * DIM + hi * 8;
#pragma unroll
    for (int kk = 0; kk < 8; ++kk)
      qf[kk] = *reinterpret_cast<const short8*>(qrow + kk * 16);
  }

  f32x16 accO[4];
#pragma unroll
  for (int td = 0; td < 4; ++td)
#pragma unroll
    for (int r = 0; r < 16; ++r) accO[td][r] = 0.f;

  // ---- prologue: stage first tile into buf 0 ----
  {
    const int vt = tile_lo * ETILE;
#pragma unroll
    for (int i = 0; i < 2; ++i)
      gll16(ebf + (size_t)(vt + i * 16 + rE) * DIM + cE, &sE[0][(i * 256 + t) * 8]);
#pragma unroll
    for (int i = 0; i < 2; ++i)
      gll16(etbf + (size_t)(i * 64 + rT) * NENTP + vt + cT, &sET[0][(i * 256 + t) * 8]);
    if (t < ETILE) sBias[0][t] = (vt + t < NENT) ? bias[vt + t] : 0.f;
  }
  __syncthreads();

  int cur = 0;
  for (int tile = tile_lo; tile < tile_hi; ++tile) {
    // ---- issue next-tile stage into cur^1 (overlaps with whole tile compute) ----
    if (tile + 1 < tile_hi) {
      const int vt = (tile + 1) * ETILE;
#pragma unroll
      for (int i = 0; i < 2; ++i)
        gll16(ebf + (size_t)(vt + i * 16 + rE) * DIM + cE,
              &sE[cur ^ 1][(i * 256 + t) * 8]);
#pragma unroll
      for (int i = 0; i < 2; ++i)
        gll16(etbf + (size_t)(i * 64 + rT) * NENTP + vt + cT,
              &sET[cur ^ 1][(i * 256 + t) * 8]);
      if (t < ETILE) sBias[cur ^ 1][t] = (vt + t < NENT) ? bias[vt + t] : 0.f;
    }

    // ---- S^T = Etile_scaled @ Q^T : wave computes S^T[32e][32q] ----
    // two independent accumulator chains (even/odd kk) -> 2-way MFMA ILP;
    // accA+accB reg r holds S^T[e = (r&3)+8*(r>>2)+4*hi][q = l31]
    const unsigned short* sEc = sE[cur];
    const float* sb = sBias[cur];
    f32x16 accA, accB;
#pragma unroll
    for (int r = 0; r < 16; ++r) { accA[r] = 0.f; accB[r] = 0.f; }

    __builtin_amdgcn_s_setprio(1);
#pragma unroll
    for (int kk = 0; kk < 4; ++kk) {
      const int colA = ((kk * 4 + hi) ^ (l31 & 15)) * 8;        // chunk of kk'=2kk
      const int colB = ((kk * 4 + 2 + hi) ^ (l31 & 15)) * 8;    // chunk of kk'=2kk+1
      short8 a0 = *reinterpret_cast<const short8*>(&sEc[l31 * 128 + colA]);
      short8 a1 = *reinterpret_cast<const short8*>(&sEc[l31 * 128 + colB]);
      accA = __builtin_amdgcn_mfma_f32_32x32x16_bf16(a0, qf[2 * kk], accA, 0, 0, 0);
      accB = __builtin_amdgcn_mfma_f32_32x32x16_bf16(a1, qf[2 * kk + 1], accB, 0, 0, 0);
    }
    __builtin_amdgcn_s_setprio(0);

    // ---- P = relu(accA + accB + bias); repack in-register to O-phase A-frags ----
    short8 F[2];  // F[ke]: P[q = l31][e = ke*16 + hi*8 + j]
    {
      float p[16];
#pragma unroll
      for (int g = 0; g < 4; ++g) {
        f32x4 b4 = *reinterpret_cast<const f32x4*>(&sb[g * 8 + hi * 4]);
#pragma unroll
        for (int j = 0; j < 4; ++j)
          p[g * 4 + j] = fmaxf(accA[g * 4 + j] + accB[g * 4 + j] + b4[j], 0.f);
      }
      unsigned wr[8];
#pragma unroll
      for (int c2 = 0; c2 < 8; ++c2) wr[c2] = cvtpk(p[2 * c2], p[2 * c2 + 1]);
      uint2v r02 = __builtin_amdgcn_permlane32_swap(wr[0], wr[2], false, false);
      uint2v r13 = __builtin_amdgcn_permlane32_swap(wr[1], wr[3], false, false);
      uint2v r46 = __builtin_amdgcn_permlane32_swap(wr[4], wr[6], false, false);
      uint2v r57 = __builtin_amdgcn_permlane32_swap(wr[5], wr[7], false, false);
      union { unsigned u[4]; short8 s; } f0, f1;
      f0.u[0] = r02[0]; f0.u[1] = r13[0]; f0.u[2] = r02[1]; f0.u[3] = r13[1];
      f1.u[0] = r46[0]; f1.u[1] = r57[0]; f1.u[2] = r46[1]; f1.u[3] = r57[1];
      F[0] = f0.s;
      F[1] = f1.s;
    }

    // ---- O += P @ Etile : wave computes O[32q][128d] ----
    const unsigned short* sTc = sET[cur];
    const int keyT = (l31 >> 2) & 3;           // = (d>>2)&3 for d = td*32 + l31
    __builtin_amdgcn_s_setprio(1);
#pragma unroll
    for (int ke = 0; ke < 2; ++ke) {
      const int col = ((ke * 2 + hi) ^ keyT) * 8;  // swizzled 16B chunk
#pragma unroll
      for (int td = 0; td < 4; ++td) {
        const int d = td * 32 + l31;
        short8 bT = *reinterpret_cast<const short8*>(&sTc[d * ETILE + col]);
        accO[td] = __builtin_amdgcn_mfma_f32_32x32x16_bf16(F[ke], bT, accO[td], 0, 0, 0);
      }
    }
    __builtin_amdgcn_s_setprio(0);

    __syncthreads();   // drains vmcnt (prefetch landed) + lgkm; swap buffers
    cur ^= 1;
  }

  // ---- epilogue: atomic accumulate partial O into f32 output ----
#pragma unroll
  for (int td = 0; td < 4; ++td) {
#pragma unroll
    for (int r = 0; r < 16; ++r) {
      int qrow = (r & 3) + 8 * (r >> 2) + 4 * hi;
      int row = m0 + w * 32 + qrow;
      int col = td * 32 + l31;
      atomicAdd(&out[(size_t)row * DIM + col], accO[td][r]);
    }
  }
}

extern "C" void kernel_launch(void* const* d_in, const int* in_sizes, int n_in,
                              void* d_out, int out_size, void* d_ws, size_t ws_size,
                              hipStream_t stream) {
  const float* x     = (const float*)d_in[0];
  const int*   ei    = (const int*)d_in[1];
  const int*   rid   = (const int*)d_in[2];
  const int*   nf    = (const int*)d_in[3];
  const float* rel   = (const float*)d_in[4];
  const float* ent   = (const float*)d_in[5];
  const float* scale = (const float*)d_in[6];
  const float* bias  = (const float*)d_in[7];
  float* out = (float*)d_out;

  // workspace layout (~28.4 MB)
  char* ws = (char*)d_ws;
  int*            cnt    = (int*)(ws + 0);                 // 16 KB
  int*            off    = (int*)(ws + (16u << 10));       // 16.4 KB
  int*            cur    = (int*)(ws + (36u << 10));       // 16 KB
  int*            sorted = (int*)(ws + (64u << 10));       // 1 MB
  unsigned short* qb     = (unsigned short*)(ws + (1344u << 10)); // 1 MB
  unsigned short* ebf    = (unsigned short*)(ws + (2560u << 10)); // 12.81 MB
  unsigned short* etbf   = (unsigned short*)(ws + (2560u << 10) + (size_t)NENTP * DIM * 2);

  hipMemsetAsync(cnt, 0, 4096 * sizeof(int), stream);
  hipMemsetAsync(d_out, 0, (size_t)out_size * sizeof(float), stream);
  k_prep<<<PREPB + NEDGES / 256, 256, 0, stream>>>(ent, scale, ebf, etbf, ei, cnt);
  k_scan<<<1, 1024, 0, stream>>>(cnt, off, cur);
  k_place<<<NEDGES / 256, 256, 0, stream>>>(ei, rid, nf, cur, sorted);
  k_aggr<<<NNODES, 256, 0, stream>>>(off, sorted, x, rel, qb);
  k_flash<<<dim3(NNODES / 128, NSPLIT), 256, 0, stream>>>(qb, ebf, etbf, bias, out);
}